// Round 13
// baseline (100.058 us; speedup 1.0000x reference)
//
#include <hip/hip_runtime.h>
#include <hip/hip_bf16.h>
#include <stdint.h>

// Problem constants: B=4, N=4096, C=1024, H=16, d=64
typedef __attribute__((ext_vector_type(8))) short bf16x8;
typedef __attribute__((ext_vector_type(4))) short bf16x4;
typedef __attribute__((ext_vector_type(4))) float f32x4;
typedef __attribute__((ext_vector_type(4))) int   i32x4;

static __device__ __forceinline__ short f2bs(float f) {
  __hip_bfloat16 h = __float2bfloat16(f);
  return __builtin_bit_cast(short, h);
}

// ---------------------------------------------------------------------------
// Fragment-blocked layouts (both produced by us, consumed by gemm_direct):
//  A'[row][k] at elem  (row>>7)*131072 + (k>>5)*4096 + ((row>>4)&7)*512
//                     + (row&15)*32 + (k&31)
//  (per (mtile,kstep,mfrag): 16 rows x 32 k = 1 KB contiguous = one wave's
//   bf16x8 fragment load, 64 lanes x 16B, perfectly coalesced)
//  W' identical with col as row.
// ---------------------------------------------------------------------------

// ---------------------------------------------------------------------------
// Kernel 1: per-token head-mix attention + fused W fp32->bf16 conversion.
// Core unchanged; only the A/W store addressing switched to blocked layout.
// ---------------------------------------------------------------------------
__global__ __launch_bounds__(256) void attn_kernel(
    const float* __restrict__ x, const float* __restrict__ y,
    __hip_bfloat16* __restrict__ A,
    const float* __restrict__ W, __hip_bfloat16* __restrict__ Wb)
{
  if (blockIdx.x < 1024) {
    const int i = (blockIdx.x * 256 + threadIdx.x) * 4;   // flat [n][k], k%4==0
    const float4 v = *(const float4*)(W + i);
    const int nW = i >> 10, kW = i & 1023;
    const size_t o = (size_t)(nW >> 7) * 131072 + (size_t)(kW >> 5) * 4096
                   + (size_t)((nW >> 4) & 7) * 512 + (nW & 15) * 32 + (kW & 31);
    Wb[o + 0] = __float2bfloat16(v.x);
    Wb[o + 1] = __float2bfloat16(v.y);
    Wb[o + 2] = __float2bfloat16(v.z);
    Wb[o + 3] = __float2bfloat16(v.w);
  }

  const int wid  = threadIdx.x >> 6;
  const int lane = threadIdx.x & 63;
  const int tok  = blockIdx.x * 4 + wid;        // 0..16383
  const int b    = tok >> 12;
  const int n    = tok & 4095;

  const float* xr = x + (size_t)tok * 1024;
  const float* yr = y + (size_t)tok * 1024;

  const int c  = lane & 15;
  const int qq = lane >> 4;

  const int fbase = c * 64 + qq * 8;
  bf16x8 yf[2], xf[2];
  #pragma unroll
  for (int kk = 0; kk < 2; ++kk) {
    const float4 a0 = *(const float4*)(yr + fbase + kk * 32);
    const float4 a1 = *(const float4*)(yr + fbase + kk * 32 + 4);
    const float4 b0 = *(const float4*)(xr + fbase + kk * 32);
    const float4 b1 = *(const float4*)(xr + fbase + kk * 32 + 4);
    yf[kk] = bf16x8{f2bs(a0.x), f2bs(a0.y), f2bs(a0.z), f2bs(a0.w),
                    f2bs(a1.x), f2bs(a1.y), f2bs(a1.z), f2bs(a1.w)};
    xf[kk] = bf16x8{f2bs(b0.x), f2bs(b0.y), f2bs(b0.z), f2bs(b0.w),
                    f2bs(b1.x), f2bs(b1.y), f2bs(b1.z), f2bs(b1.w)};
  }

  f32x4 acc = {0.f, 0.f, 0.f, 0.f};
  acc = __builtin_amdgcn_mfma_f32_16x16x32_bf16(yf[0], xf[0], acc, 0, 0, 0);
  acc = __builtin_amdgcn_mfma_f32_16x16x32_bf16(yf[1], xf[1], acc, 0, 0, 0);

  float sc[4];
  #pragma unroll
  for (int r = 0; r < 4; ++r) sc[r] = acc[r] * 0.125f;
  float mx = fmaxf(fmaxf(sc[0], sc[1]), fmaxf(sc[2], sc[3]));
  mx = fmaxf(mx, __shfl_xor(mx, 16));
  mx = fmaxf(mx, __shfl_xor(mx, 32));
  float e[4];
  #pragma unroll
  for (int r = 0; r < 4; ++r) e[r] = __expf(sc[r] - mx);
  float sm = (e[0] + e[1]) + (e[2] + e[3]);
  sm += __shfl_xor(sm, 16);
  sm += __shfl_xor(sm, 32);
  const float inv = 1.0f / sm;
  float p[4];
  #pragma unroll
  for (int r = 0; r < 4; ++r) p[r] = e[r] * inv;

  f32x4 o[4];
  #pragma unroll
  for (int q = 0; q < 4; ++q) o[q] = f32x4{0.f, 0.f, 0.f, 0.f};

#if __has_builtin(__builtin_amdgcn_mfma_f32_16x16x16bf16_1k)
  const bf16x4 pa = {f2bs(p[0]), f2bs(p[1]), f2bs(p[2]), f2bs(p[3])};
  #pragma unroll
  for (int q = 0; q < 4; ++q) {
    bf16x4 bq;
    #pragma unroll
    for (int j = 0; j < 4; ++j)
      bq[j] = f2bs(yr[(qq * 4 + j) * 64 + q * 16 + c]);
    o[q] = __builtin_amdgcn_mfma_f32_16x16x16bf16_1k(pa, bq, o[q], 0, 0, 0);
  }
#else
  const int u0 = ((int)(unsigned short)f2bs(p[1]) << 16) | (unsigned short)f2bs(p[0]);
  const int u1 = ((int)(unsigned short)f2bs(p[3]) << 16) | (unsigned short)f2bs(p[2]);
  const int s0 = c + 32 * qq;
  int a0 = __shfl(u0, s0), a1 = __shfl(u1, s0);
  int a2 = __shfl(u0, s0 + 16), a3 = __shfl(u1, s0 + 16);
  const bool valid = (qq < 2);
  if (!valid) { a0 = 0; a1 = 0; a2 = 0; a3 = 0; }
  const bf16x8 a8 = __builtin_bit_cast(bf16x8, i32x4{a0, a1, a2, a3});
  #pragma unroll
  for (int q = 0; q < 4; ++q) {
    bf16x8 b8;
    #pragma unroll
    for (int j = 0; j < 8; ++j) {
      const int g = (qq * 8 + j) & 15;
      const float v = yr[g * 64 + q * 16 + c];
      b8[j] = valid ? f2bs(v) : (short)0;
    }
    o[q] = __builtin_amdgcn_mfma_f32_16x16x32_bf16(a8, b8, o[q], 0, 0, 0);
  }
#endif

  // ---- store O into fragment-blocked A' ----
  // row = b*4096 + h*256 + n16;  k = (n&15)*64 + q*16 + c
  // mt = b*32 + h*2 + (n16>>7); ks = (n&15)*2 + (q>>1); mf = (n16>>4)&7;
  // fr = n16&15; ko = (q&1)*16 + c.  (h term = h*262144 elems)
  const int n16 = n >> 4;
  const size_t base2 = (size_t)(b * 32 + (n16 >> 7)) * 131072
                     + (size_t)((n & 15) * 2) * 4096
                     + (size_t)((n16 >> 4) & 7) * 512 + (n16 & 15) * 32 + c;
  #pragma unroll
  for (int q = 0; q < 4; ++q)
    #pragma unroll
    for (int r = 0; r < 4; ++r) {
      const int h = qq * 4 + r;
      A[base2 + (size_t)h * 262144 + (q >> 1) * 4096 + (q & 1) * 16] =
          __float2bfloat16(o[q][r]);
    }
}

// ---------------------------------------------------------------------------
// Kernel 2: ZERO-LDS streaming GEMM  out[M,Nn] = A'[M,K]*W'[Nn,K]^T + bias.
// Block 128x128 (4 waves 2x2, wave 64x64, acc[4][4]); per K-step each lane:
// 4 A-frag + 4 B-frag global_load_dwordx4 (each = one contiguous 1 KB block
// per wave, L2-resident) + 16 MFMAs. Register parity-2 double buffer.
// No LDS, no barriers, no waitcnt asm — 12 independent waves/CU drift freely
// (3 blocks/CU at ~140 VGPR). Bijective XCD chunking: A-panel (256 KB)
// reused 8x per XCD, W' (2 MB) pinned per XCD L2.
// ---------------------------------------------------------------------------
#define SP1   __builtin_amdgcn_s_setprio(1)
#define SP0   __builtin_amdgcn_s_setprio(0)

__global__ __launch_bounds__(256, 3) void gemm_direct(
    const __hip_bfloat16* __restrict__ A,   // A' blocked, M=16384
    const __hip_bfloat16* __restrict__ Bw,  // W' blocked, Nn=1024
    const float* __restrict__ bias,         // [Nn]
    float* __restrict__ C)                  // [M, Nn] fp32 row-major
{
  const int tid  = threadIdx.x;             // 0..255
  const int lane = tid & 63;
  const int wid  = tid >> 6;                // 4 waves: 2M x 2N
  const int wr   = wid >> 1;                // 0..1
  const int wcN  = wid & 1;                 // 0..1

  // bijective XCD chunking: 1024 blocks = 8 XCDs x 128; nt varies fastest
  const int bid = blockIdx.x;
  const int nb  = (bid & 7) * 128 + (bid >> 3);
  const int mt  = nb >> 3;                  // 0..127 (128-row tile)
  const int nt  = nb & 7;                   // 0..7   (128-col tile)

  const int fr = lane & 15;
  const int kq = lane >> 4;

  // fragment base pointers (elements); frag f: +f*512, kstep ks: +ks*4096
  const __hip_bfloat16* aP = A  + (size_t)mt * 131072 + (wr  * 4) * 512
                           + fr * 32 + kq * 8;
  const __hip_bfloat16* bP = Bw + (size_t)nt * 131072 + (wcN * 4) * 512
                           + fr * 32 + kq * 8;

  f32x4 acc[4][4];
  #pragma unroll
  for (int m = 0; m < 4; ++m)
    #pragma unroll
    for (int n = 0; n < 4; ++n) acc[m][n] = f32x4{0.f, 0.f, 0.f, 0.f};

  bf16x8 A0[4], B0[4], A1[4], B1[4];

  // prologue: ksteps 0,1
  #pragma unroll
  for (int f = 0; f < 4; ++f) {
    A0[f] = *(const bf16x8*)(aP + f * 512);
    B0[f] = *(const bf16x8*)(bP + f * 512);
  }
  #pragma unroll
  for (int f = 0; f < 4; ++f) {
    A1[f] = *(const bf16x8*)(aP + 4096 + f * 512);
    B1[f] = *(const bf16x8*)(bP + 4096 + f * 512);
  }

  #pragma unroll 2
  for (int ks = 0; ks < 32; ks += 2) {
    const int k2 = (ks + 2) & 31;           // wraps harmlessly at the tail
    const int k3 = (ks + 3) & 31;
    // parity 0: MFMA(ks), prefetch ks+2
    SP1;
    #pragma unroll
    for (int m = 0; m < 4; ++m)
      #pragma unroll
      for (int n = 0; n < 4; ++n)
        acc[m][n] = __builtin_amdgcn_mfma_f32_16x16x32_bf16(A0[m], B0[n], acc[m][n], 0, 0, 0);
    SP0;
    #pragma unroll
    for (int f = 0; f < 4; ++f) {
      A0[f] = *(const bf16x8*)(aP + k2 * 4096 + f * 512);
      B0[f] = *(const bf16x8*)(bP + k2 * 4096 + f * 512);
    }
    // parity 1: MFMA(ks+1), prefetch ks+3
    SP1;
    #pragma unroll
    for (int m = 0; m < 4; ++m)
      #pragma unroll
      for (int n = 0; n < 4; ++n)
        acc[m][n] = __builtin_amdgcn_mfma_f32_16x16x32_bf16(A1[m], B1[n], acc[m][n], 0, 0, 0);
    SP0;
    #pragma unroll
    for (int f = 0; f < 4; ++f) {
      A1[f] = *(const bf16x8*)(aP + k3 * 4096 + f * 512);
      B1[f] = *(const bf16x8*)(bP + k3 * 4096 + f * 512);
    }
  }

  // epilogue: C/D layout col=lane&15, row=(lane>>4)*4+reg
  #pragma unroll
  for (int n = 0; n < 4; ++n) {
    const int col = nt * 128 + wcN * 64 + n * 16 + fr;
    const float bv = bias[col];
    #pragma unroll
    for (int m = 0; m < 4; ++m) {
      const int row0 = mt * 128 + wr * 64 + m * 16 + kq * 4;
      #pragma unroll
      for (int r = 0; r < 4; ++r)
        C[(size_t)(row0 + r) * 1024 + col] = acc[m][n][r] + bv;
    }
  }
}

extern "C" void kernel_launch(void* const* d_in, const int* in_sizes, int n_in,
                              void* d_out, int out_size, void* d_ws, size_t ws_size,
                              hipStream_t stream) {
  const float* x    = (const float*)d_in[0];
  const float* y    = (const float*)d_in[1];
  const float* W    = (const float*)d_in[2];
  const float* bias = (const float*)d_in[3];
  float* out = (float*)d_out;

  // Workspace: A' (16384x1024 bf16 = 32 MB) + W' (2 MB)
  __hip_bfloat16* Abuf = (__hip_bfloat16*)d_ws;
  __hip_bfloat16* Wbuf = (__hip_bfloat16*)((char*)d_ws + (size_t)16384 * 1024 * 2);

  attn_kernel<<<4096, 256, 0, stream>>>(x, y, Abuf, W, Wbuf);
  gemm_direct<<<1024, 256, 0, stream>>>(Abuf, Wbuf, bias, out);
}